// Round 2
// baseline (1459.737 us; speedup 1.0000x reference)
//
#include <hip/hip_runtime.h>
#include <hip/hip_bf16.h>

#define T_TOK 2048
#define HID   2048
#define NEXP  8
#define INTER 1408

typedef float f32x4 __attribute__((ext_vector_type(4)));
typedef __bf16 bf16x8 __attribute__((ext_vector_type(8)));
typedef unsigned int u32;

__device__ __forceinline__ u32 pk(__bf16 a, __bf16 b) {
    return (u32)__builtin_bit_cast(unsigned short, a) |
           ((u32)__builtin_bit_cast(unsigned short, b) << 16);
}

// split fp32[8] -> packed hi/lo bf16 uint4s (hi = rne(bf16), lo = rne(v - hi))
__device__ __forceinline__ void pack8(const float* v, uint4& hi, uint4& lo) {
    __bf16 h[8];
#pragma unroll
    for (int j = 0; j < 8; ++j) h[j] = (__bf16)v[j];
    hi.x = pk(h[0], h[1]); hi.y = pk(h[2], h[3]);
    hi.z = pk(h[4], h[5]); hi.w = pk(h[6], h[7]);
    float r[8];
#pragma unroll
    for (int j = 0; j < 8; ++j) r[j] = v[j] - (float)h[j];
    lo.x = pk((__bf16)r[0], (__bf16)r[1]); lo.y = pk((__bf16)r[2], (__bf16)r[3]);
    lo.z = pk((__bf16)r[4], (__bf16)r[5]); lo.w = pk((__bf16)r[6], (__bf16)r[7]);
}

// async global->LDS 16B: per-lane global src, wave-uniform LDS base (+lane*16 in HW)
__device__ __forceinline__ void dma16(const __bf16* g, __bf16* ldsWaveBase, int lane) {
#if __has_builtin(__builtin_amdgcn_global_load_lds)
    __builtin_amdgcn_global_load_lds(
        (const __attribute__((address_space(1))) u32*)g,
        (__attribute__((address_space(3))) u32*)ldsWaveBase, 16, 0, 0);
#else
    *reinterpret_cast<bf16x8*>(ldsWaveBase + lane * 8) =
        *reinterpret_cast<const bf16x8*>(g);
#endif
}

// ---------------- Router: logits -> top2 -> normalized weights -> expert lists
__global__ __launch_bounds__(256)
void router_kernel(const float* __restrict__ hs, const float* __restrict__ gw,
                   int* __restrict__ cnt, int* __restrict__ list,
                   float* __restrict__ wslot)
{
    const int wv = threadIdx.x >> 6, lane = threadIdx.x & 63;
    const int t = blockIdx.x * 4 + wv;
    float acc[8];
#pragma unroll
    for (int e = 0; e < 8; ++e) acc[e] = 0.f;
    const float* xr = hs + (size_t)t * HID;
    for (int it = 0; it < HID / 256; ++it) {
        const int h = it * 256 + lane * 4;
        float4 x = *reinterpret_cast<const float4*>(xr + h);
#pragma unroll
        for (int e = 0; e < 8; ++e) {
            float4 g = *reinterpret_cast<const float4*>(gw + e * HID + h);
            acc[e] += x.x * g.x + x.y * g.y + x.z * g.z + x.w * g.w;
        }
    }
#pragma unroll
    for (int e = 0; e < 8; ++e) {
#pragma unroll
        for (int off = 32; off >= 1; off >>= 1)
            acc[e] += __shfl_xor(acc[e], off, 64);
    }
    if (lane == 0) {
        int b0 = 0, b1 = -1;
        float v0 = -1e30f, v1 = -1e30f;
#pragma unroll
        for (int e = 0; e < 8; ++e) {
            if (acc[e] > v0) { v1 = v0; b1 = b0; v0 = acc[e]; b0 = e; }
            else if (acc[e] > v1) { v1 = acc[e]; b1 = e; }
        }
        float w0 = 1.f / (1.f + __expf(v1 - v0));  // p0/(p0+p1)
        float w1 = 1.f - w0;
        int p0 = atomicAdd(&cnt[b0], 1);
        list[b0 * T_TOK + p0] = 2 * t;
        wslot[2 * t] = w0;
        int p1 = atomicAdd(&cnt[b1], 1);
        list[b1 * T_TOK + p1] = 2 * t + 1;
        wslot[2 * t + 1] = w1;
    }
}

// ---------------- X fp32 -> bf16 hi/lo (linear layout, enables DMA A-staging)
__global__ __launch_bounds__(256)
void pack_x(const float* __restrict__ x, __bf16* __restrict__ xh, __bf16* __restrict__ xl)
{
    size_t i = ((size_t)blockIdx.x * 256 + threadIdx.x) * 4;
    float4 v = *reinterpret_cast<const float4*>(x + i);
    __bf16 h0 = (__bf16)v.x, h1 = (__bf16)v.y, h2 = (__bf16)v.z, h3 = (__bf16)v.w;
    uint2 hi, lo;
    hi.x = pk(h0, h1); hi.y = pk(h2, h3);
    lo.x = pk((__bf16)(v.x - (float)h0), (__bf16)(v.y - (float)h1));
    lo.y = pk((__bf16)(v.z - (float)h2), (__bf16)(v.w - (float)h3));
    *reinterpret_cast<uint2*>(xh + i) = hi;
    *reinterpret_cast<uint2*>(xl + i) = lo;
}

// ---------------- Fused gate+up grouped GEMM. Tile 128x64, 4 waves (each 64x32
// per matrix), 3-pass split-bf16 MFMA. LDS chunk layouts [kg][row][8] so all
// ds ops are contiguous-256B per quarter-wave (conflict-free).
__global__ __launch_bounds__(256, 3)
void moe_gateup(const __bf16* __restrict__ xh, const __bf16* __restrict__ xl,
                const float* __restrict__ wgAll, const float* __restrict__ wuAll,
                const int* __restrict__ cnt, const int* __restrict__ list,
                __bf16* __restrict__ actH, __bf16* __restrict__ actL)
{
    const int e = blockIdx.z;
    const int cntE = cnt[e];
    const int rb = blockIdx.x * 128;
    if (rb >= cntE) return;
    const int nb = blockIdx.y;
    const int tid = threadIdx.x, lane = tid & 63, wv = tid >> 6;
    const int wr = (wv >> 1) * 64, wc = (wv & 1) * 32;
    const int p = lane & 15, kg = lane >> 4;

    __shared__ __bf16 AhL[4096], AlL[4096];                              // [4][128][8]
    __shared__ __bf16 BghL[2048], BglL[2048], BuhL[2048], BulL[2048];    // [4][64][8]
    __shared__ int slots[128];

    if (tid < 128) {
        int r = rb + tid;
        slots[tid] = (r < cntE) ? list[e * T_TOK + r] : 0;
    }
    __syncthreads();

    // A staging: thread covers chunks tid (kg=tid>>7) and tid+256 (kg+2), row=tid&127
    const size_t tok = (size_t)(slots[tid & 127] >> 1);
    const __bf16* aSrcH = xh + tok * HID + (tid >> 7) * 8;
    const __bf16* aSrcL = xl + tok * HID + (tid >> 7) * 8;
    __bf16* aDst0h = &AhL[(wv * 64) * 8];
    __bf16* aDst1h = &AhL[(256 + wv * 64) * 8];
    __bf16* aDst0l = &AlL[(wv * 64) * 8];
    __bf16* aDst1l = &AlL[(256 + wv * 64) * 8];

    // B conversion: thread == chunk tid (kgB=tid>>6, nB=tid&63) in both matrices.
    // Per j, a wave reads 64 consecutive floats (coalesced); writes are
    // lane-consecutive b128 (contiguous 1024B per wave).
    const size_t wbase = (size_t)e * HID * INTER + (size_t)((tid >> 6) * 8) * INTER
                       + (size_t)nb * 64 + (tid & 63);
    const float* bgSrc = wgAll + wbase;
    const float* buSrc = wuAll + wbase;

    f32x4 accG[4][2], accU[4][2];
#pragma unroll
    for (int i = 0; i < 4; ++i)
#pragma unroll
        for (int j = 0; j < 2; ++j) { accG[i][j] = (f32x4)0.f; accU[i][j] = (f32x4)0.f; }

    float bg[8], bu[8];

#define LOADB(kb) { \
    const float* s1_ = bgSrc + (size_t)(kb) * INTER; \
    const float* s2_ = buSrc + (size_t)(kb) * INTER; \
    _Pragma("unroll") for (int j = 0; j < 8; ++j) bg[j] = s1_[(size_t)j * INTER]; \
    _Pragma("unroll") for (int j = 0; j < 8; ++j) bu[j] = s2_[(size_t)j * INTER]; }

#define STAGEA(kb) { \
    dma16(aSrcH + (kb),      aDst0h, lane); \
    dma16(aSrcH + (kb) + 16, aDst1h, lane); \
    dma16(aSrcL + (kb),      aDst0l, lane); \
    dma16(aSrcL + (kb) + 16, aDst1l, lane); }

#define WRITEB() { \
    uint4 h_, l_; \
    pack8(bg, h_, l_); \
    *reinterpret_cast<uint4*>(&BghL[tid * 8]) = h_; \
    *reinterpret_cast<uint4*>(&BglL[tid * 8]) = l_; \
    pack8(bu, h_, l_); \
    *reinterpret_cast<uint4*>(&BuhL[tid * 8]) = h_; \
    *reinterpret_cast<uint4*>(&BulL[tid * 8]) = l_; }

    LOADB(0); STAGEA(0); WRITEB();
    __syncthreads();

    for (int kt = 0; kt < HID / 32; ++kt) {
        bf16x8 ah[4], al[4], bgh[2], bgl[2], buh[2], bul[2];
#pragma unroll
        for (int mi = 0; mi < 4; ++mi) {
            int off = (kg * 128 + wr + mi * 16 + p) * 8;
            ah[mi] = *reinterpret_cast<const bf16x8*>(&AhL[off]);
            al[mi] = *reinterpret_cast<const bf16x8*>(&AlL[off]);
        }
#pragma unroll
        for (int ni = 0; ni < 2; ++ni) {
            int off = (kg * 64 + wc + ni * 16 + p) * 8;
            bgh[ni] = *reinterpret_cast<const bf16x8*>(&BghL[off]);
            bgl[ni] = *reinterpret_cast<const bf16x8*>(&BglL[off]);
            buh[ni] = *reinterpret_cast<const bf16x8*>(&BuhL[off]);
            bul[ni] = *reinterpret_cast<const bf16x8*>(&BulL[off]);
        }
        __syncthreads();                       // all LDS reads done -> safe to restage
        const bool more = (kt + 1) < (HID / 32);
        if (more) { STAGEA((kt + 1) * 32); LOADB((kt + 1) * 32); }
#pragma unroll
        for (int mi = 0; mi < 4; ++mi)
#pragma unroll
            for (int ni = 0; ni < 2; ++ni) {
                accG[mi][ni] = __builtin_amdgcn_mfma_f32_16x16x32_bf16(ah[mi], bgh[ni], accG[mi][ni], 0, 0, 0);
                accG[mi][ni] = __builtin_amdgcn_mfma_f32_16x16x32_bf16(ah[mi], bgl[ni], accG[mi][ni], 0, 0, 0);
                accG[mi][ni] = __builtin_amdgcn_mfma_f32_16x16x32_bf16(al[mi], bgh[ni], accG[mi][ni], 0, 0, 0);
                accU[mi][ni] = __builtin_amdgcn_mfma_f32_16x16x32_bf16(ah[mi], buh[ni], accU[mi][ni], 0, 0, 0);
                accU[mi][ni] = __builtin_amdgcn_mfma_f32_16x16x32_bf16(ah[mi], bul[ni], accU[mi][ni], 0, 0, 0);
                accU[mi][ni] = __builtin_amdgcn_mfma_f32_16x16x32_bf16(al[mi], buh[ni], accU[mi][ni], 0, 0, 0);
            }
        if (more) { WRITEB(); }
        __syncthreads();                       // staging (DMA vmcnt + ds_writes) complete
    }
#undef LOADB
#undef STAGEA
#undef WRITEB

    // epilogue: a = silu(g)*u -> bf16 hi/lo act. C/D: col=lane&15, row=(lane>>4)*4+j
    const size_t nb64 = (size_t)nb * 64;
#pragma unroll
    for (int mi = 0; mi < 4; ++mi)
#pragma unroll
        for (int j = 0; j < 4; ++j) {
            int lr = wr + mi * 16 + kg * 4 + j;
            if (rb + lr < cntE) {
                size_t rowoff = (size_t)slots[lr] * INTER + nb64;
#pragma unroll
                for (int ni = 0; ni < 2; ++ni) {
                    int col = wc + ni * 16 + p;
                    float g = accG[mi][ni][j], u = accU[mi][ni][j];
                    float a = g / (1.f + __expf(-g)) * u;
                    __bf16 h = (__bf16)a;
                    actH[rowoff + col] = h;
                    actL[rowoff + col] = (__bf16)(a - (float)h);
                }
            }
        }
}

// ---------------- Down grouped GEMM. Tile 128x64, atomic weighted combine.
__global__ __launch_bounds__(256, 4)
void moe_down(const __bf16* __restrict__ actH, const __bf16* __restrict__ actL,
              const float* __restrict__ wdAll,
              const int* __restrict__ cnt, const int* __restrict__ list,
              const float* __restrict__ wslot, float* __restrict__ out)
{
    const int e = blockIdx.z;
    const int cntE = cnt[e];
    const int rb = blockIdx.x * 128;
    if (rb >= cntE) return;
    const int nb = blockIdx.y;
    const int tid = threadIdx.x, lane = tid & 63, wv = tid >> 6;
    const int wr = (wv >> 1) * 64, wc = (wv & 1) * 32;
    const int p = lane & 15, kg = lane >> 4;

    __shared__ __bf16 AhL[4096], AlL[4096];        // [4][128][8]
    __shared__ __bf16 BhL[2048], BlL[2048];        // [4][64][8]
    __shared__ int slots[128];

    if (tid < 128) {
        int r = rb + tid;
        slots[tid] = (r < cntE) ? list[e * T_TOK + r] : 0;
    }
    __syncthreads();

    const __bf16* aSrcH = actH + (size_t)slots[tid & 127] * INTER + (tid >> 7) * 8;
    const __bf16* aSrcL = actL + (size_t)slots[tid & 127] * INTER + (tid >> 7) * 8;
    __bf16* aDst0h = &AhL[(wv * 64) * 8];
    __bf16* aDst1h = &AhL[(256 + wv * 64) * 8];
    __bf16* aDst0l = &AlL[(wv * 64) * 8];
    __bf16* aDst1l = &AlL[(256 + wv * 64) * 8];

    const float* bdSrc = wdAll + (size_t)e * INTER * HID
                       + (size_t)((tid >> 6) * 8) * HID + (size_t)nb * 64 + (tid & 63);

    f32x4 acc[4][2];
#pragma unroll
    for (int i = 0; i < 4; ++i)
#pragma unroll
        for (int j = 0; j < 2; ++j) acc[i][j] = (f32x4)0.f;

    float bd[8];

#define LOADB(kb) { \
    const float* s1_ = bdSrc + (size_t)(kb) * HID; \
    _Pragma("unroll") for (int j = 0; j < 8; ++j) bd[j] = s1_[(size_t)j * HID]; }

#define STAGEA(kb) { \
    dma16(aSrcH + (kb),      aDst0h, lane); \
    dma16(aSrcH + (kb) + 16, aDst1h, lane); \
    dma16(aSrcL + (kb),      aDst0l, lane); \
    dma16(aSrcL + (kb) + 16, aDst1l, lane); }

#define WRITEB() { \
    uint4 h_, l_; \
    pack8(bd, h_, l_); \
    *reinterpret_cast<uint4*>(&BhL[tid * 8]) = h_; \
    *reinterpret_cast<uint4*>(&BlL[tid * 8]) = l_; }

    LOADB(0); STAGEA(0); WRITEB();
    __syncthreads();

    for (int kt = 0; kt < INTER / 32; ++kt) {
        bf16x8 ah[4], al[4], bh[2], bl[2];
#pragma unroll
        for (int mi = 0; mi < 4; ++mi) {
            int off = (kg * 128 + wr + mi * 16 + p) * 8;
            ah[mi] = *reinterpret_cast<const bf16x8*>(&AhL[off]);
            al[mi] = *reinterpret_cast<const bf16x8*>(&AlL[off]);
        }
#pragma unroll
        for (int ni = 0; ni < 2; ++ni) {
            int off = (kg * 64 + wc + ni * 16 + p) * 8;
            bh[ni] = *reinterpret_cast<const bf16x8*>(&BhL[off]);
            bl[ni] = *reinterpret_cast<const bf16x8*>(&BlL[off]);
        }
        __syncthreads();
        const bool more = (kt + 1) < (INTER / 32);
        if (more) { STAGEA((kt + 1) * 32); LOADB((kt + 1) * 32); }
#pragma unroll
        for (int mi = 0; mi < 4; ++mi)
#pragma unroll
            for (int ni = 0; ni < 2; ++ni) {
                acc[mi][ni] = __builtin_amdgcn_mfma_f32_16x16x32_bf16(ah[mi], bh[ni], acc[mi][ni], 0, 0, 0);
                acc[mi][ni] = __builtin_amdgcn_mfma_f32_16x16x32_bf16(ah[mi], bl[ni], acc[mi][ni], 0, 0, 0);
                acc[mi][ni] = __builtin_amdgcn_mfma_f32_16x16x32_bf16(al[mi], bh[ni], acc[mi][ni], 0, 0, 0);
            }
        if (more) { WRITEB(); }
        __syncthreads();
    }
#undef LOADB
#undef STAGEA
#undef WRITEB

    const size_t nb64 = (size_t)nb * 64;
#pragma unroll
    for (int mi = 0; mi < 4; ++mi)
#pragma unroll
        for (int j = 0; j < 4; ++j) {
            int lr = wr + mi * 16 + kg * 4 + j;
            if (rb + lr < cntE) {
                int s = slots[lr];
                float w = wslot[s];
                size_t rowoff = (size_t)(s >> 1) * HID + nb64;
#pragma unroll
                for (int ni = 0; ni < 2; ++ni) {
                    int col = wc + ni * 16 + p;
                    atomicAdd(&out[rowoff + col], acc[mi][ni][j] * w);
                }
            }
        }
}

extern "C" void kernel_launch(void* const* d_in, const int* in_sizes, int n_in,
                              void* d_out, int out_size, void* d_ws, size_t ws_size,
                              hipStream_t stream)
{
    const float* hs = (const float*)d_in[0];
    const float* gw = (const float*)d_in[1];
    const float* wg = (const float*)d_in[2];
    const float* wu = (const float*)d_in[3];
    const float* wd = (const float*)d_in[4];
    float* out = (float*)d_out;

    char* ws = (char*)d_ws;
    int*    cnt   = (int*)(ws);                                 // 32 B
    int*    list  = (int*)(ws + 256);                           // 64 KiB
    float*  wslot = (float*)(ws + 256 + 65536);                 // 16 KiB
    __bf16* Xh    = (__bf16*)(ws + 1048576);                    // 8.39 MB
    __bf16* Xl    = (__bf16*)(ws + 1048576 + 8388608);          // 8.39 MB
    __bf16* actH  = (__bf16*)(ws + 1048576 + 2 * 8388608);      // 11.53 MB
    __bf16* actL  = (__bf16*)(ws + 1048576 + 2 * 8388608 + 11534336); // 11.53 MB  (total ~40 MB)

    hipMemsetAsync(cnt, 0, 8 * sizeof(int), stream);
    hipMemsetAsync(out, 0, (size_t)out_size * sizeof(float), stream);

    pack_x<<<(T_TOK * HID / 4) / 256, 256, 0, stream>>>(hs, Xh, Xl);
    router_kernel<<<T_TOK / 4, 256, 0, stream>>>(hs, gw, cnt, list, wslot);

    // fused gate+up: tiles 128 rows x 64 cols, grid covers worst-case cntE=2048
    moe_gateup<<<dim3(16, INTER / 64, NEXP), 256, 0, stream>>>(Xh, Xl, wg, wu, cnt, list, actH, actL);
    // down: 128 x 64 tiles over H=2048 cols
    moe_down<<<dim3(16, HID / 64, NEXP), 256, 0, stream>>>(actH, actL, wd, cnt, list, wslot, out);
}